// Round 11
// baseline (120.882 us; speedup 1.0000x reference)
//
#include <hip/hip_runtime.h>
#include <hip/hip_bf16.h>

// out[b,o,n] = sum_{k,c} input[b,c,n] * weight[o,k,c] * score[b,k,n]
// B=8, C_IN=16, C_OUT=16, K=4, N=524288. fp32 in/out.
// MFMA: out[b,:,n] = W'(16x64) . Z(64,n), Z[k*16+c,n] = a[k,n]*x[c,n].
//
// r10 lesson: block-wide barrier per stage convoys all 4 waves' memory bursts
// -> only 3 independent streams/CU, loaded-latency bound at 3.7 TB/s.
// r11: per-wave quarters. Each wave glls its OWN 16x64 x-quarter (per-lane
// global addrs gather 4 rowsx64 floats per gll16) -> zero cross-wave deps ->
// NO barriers at all. 2-buf x 4KB x 4 waves = 32KB -> 5 blocks/CU = 20
// independent wave pipelines/CU, register-free MLP via gll.

constexpr int B     = 8;
constexpr int C_IN  = 16;
constexpr int C_OUT = 16;
constexpr int KK    = 4;
constexpr long NN   = 524288;            // 2^19
constexpr int S     = 8;                 // stages per block
constexpr int BPB   = (int)(NN / (256 * S));  // 256 blocks per batch
constexpr int GRID  = B * BPB;           // 2048

typedef short bf16x8 __attribute__((ext_vector_type(8)));
typedef float f32x4  __attribute__((ext_vector_type(4)));

__device__ inline short f2bf(float f) {
    return __builtin_bit_cast(short, __float2bfloat16(f));
}

// global->LDS direct copy, 16 B/lane. LDS dest = wave-uniform base + lane*16;
// global src is PER-LANE. Zero result VGPRs (tracked by vmcnt).
__device__ inline void gll16(const float* gsrc, float* ldst) {
    __builtin_amdgcn_global_load_lds(
        (const __attribute__((address_space(1))) unsigned int*)gsrc,
        (__attribute__((address_space(3))) unsigned int*)ldst,
        16, 0, 0);
}

__global__ __launch_bounds__(256, 5) void
TransformConv1d_39264591020709_kernel(const float* __restrict__ in,
                                      const float* __restrict__ w,
                                      const float* __restrict__ sc,
                                      float* __restrict__ out) {
    __shared__ float lds[2][4][C_IN][64];   // [buf][wave][row][col] = 32 KB

    const int tid  = threadIdx.x;
    const int lane = tid & 63;
    const int wid  = tid >> 6;           // wave 0..3
    const int g    = lane >> 4;          // lane group 0..3
    const int col  = lane & 15;
    const int lr   = lane >> 4;          // row-within-4 for gll/readback
    const int lc4  = (lane & 15) * 4;    // float offset for 16B lanes

    const int  bi = blockIdx.x;
    const int  b  = bi >> 8;             // / BPB (=256)
    const long n0 = (long)(bi & (BPB - 1)) * (256 * S);

    const int ktap = g >> 1;             // score taps {ktap, ktap+2}
    const int c0   = (g & 1) * 8;        // input-channel half

    // A operand (weights): lane holds W'[o=col][kc=g*8+i (+32)] (verified r6-r10).
    bf16x8 w0, w1;
#pragma unroll
    for (int i = 0; i < 8; ++i) {
        w0[i] = f2bf(w[(col * KK + ktap    ) * C_IN + c0 + i]);
        w1[i] = f2bf(w[(col * KK + ktap + 2) * C_IN + c0 + i]);
    }

    const float* inb  = in  + (long)b * C_IN  * NN;
    const float* scb  = sc  + (long)b * KK    * NN;
    float*       outb = out + (long)b * C_OUT * NN;

    // Wave-private staging: 4 gll16, each gathers rows 4j..4j+3 x 64 floats
    // of THIS wave's column quarter. Per-lane src: row 4j+lr, cols lc4..lc4+3.
    auto STAGE = [&](int s) {
        const long nw = n0 + (long)s * 256 + wid * 64;
#pragma unroll
        for (int j = 0; j < 4; ++j)
            gll16(inb + (long)(4 * j + lr) * NN + nw + lc4,
                  &lds[s & 1][wid][4 * j][0]);
    };

    auto SCORES = [&](int s, float (&a0)[4], float (&a1)[4]) {
        const long nw = n0 + (long)s * 256 + wid * 64;
#pragma unroll
        for (int u = 0; u < 4; ++u) {
            a0[u] = scb[(long)ktap       * NN + nw + u * 16 + col];
            a1[u] = scb[(long)(ktap + 2) * NN + nw + u * 16 + col];
        }
    };

    // ---- prologue: scores_0(8), glls_0(4). No barrier ever. ----
    float a0c[4], a1c[4];
    SCORES(0, a0c, a1c);
    STAGE(0);

#pragma unroll
    for (int s = 0; s < S; ++s) {
        const long nw = n0 + (long)s * 256 + wid * 64;
        float (*X)[64] = lds[s & 1][wid];

        // prefetch next stage (wave-private, in flight across this stage)
        float a0n[4], a1n[4];
        if (s + 1 < S) {
            SCORES(s + 1, a0n, a1n);
            STAGE(s + 1);
        }
        __builtin_amdgcn_sched_barrier(0);

        // wait: scores_s + glls_s retired; newer prefetch/stores stay in flight.
        // FIFO newer-than-{scores_s,glls_s}: s=0: sc_1(8)+gl_1(4)=12;
        // 1<=s<S-1: st_{s-1}(4)+sc_{s+1}(8)+gl_{s+1}(4)=16; s=S-1: st(4).
        if (s == 0)          asm volatile("s_waitcnt vmcnt(12)" ::: "memory");
        else if (s + 1 < S)  asm volatile("s_waitcnt vmcnt(16)" ::: "memory");
        else                 asm volatile("s_waitcnt vmcnt(4)"  ::: "memory");
        __builtin_amdgcn_sched_barrier(0);

        // ---- compute 4 tiles from own quarter; transpose via consumed slab ----
#pragma unroll
        for (int u = 0; u < 4; ++u) {
            float xv[8];
#pragma unroll
            for (int i = 0; i < 8; ++i) xv[i] = X[c0 + i][u * 16 + col];
            bf16x8 z0, z1;
#pragma unroll
            for (int i = 0; i < 8; ++i) {
                z0[i] = f2bf(a0c[u] * xv[i]);
                z1[i] = f2bf(a1c[u] * xv[i]);
            }
            f32x4 acc = {0.f, 0.f, 0.f, 0.f};
            acc = __builtin_amdgcn_mfma_f32_16x16x32_bf16(w0, z0, acc, 0, 0, 0);
            acc = __builtin_amdgcn_mfma_f32_16x16x32_bf16(w1, z1, acc, 0, 0, 0);
#pragma unroll
            for (int r = 0; r < 4; ++r)
                X[g * 4 + r][u * 16 + col] = acc[r];  // D[row=g*4+r][col]
        }
        __builtin_amdgcn_sched_barrier(0);

        // ---- read back (b128) and store full 256B segments, nt ----
#pragma unroll
        for (int q = 0; q < 4; ++q) {
            const int row = q * 4 + lr;
            f32x4 v = *(const f32x4*)&X[row][lc4];
            __builtin_nontemporal_store(v, (f32x4*)(outb + (long)row * NN + nw + lc4));
        }

        // rotate score regs (static indices; loop fully unrolled)
#pragma unroll
        for (int u = 0; u < 4; ++u) { a0c[u] = a0n[u]; a1c[u] = a1n[u]; }
    }
}

extern "C" void kernel_launch(void* const* d_in, const int* in_sizes, int n_in,
                              void* d_out, int out_size, void* d_ws, size_t ws_size,
                              hipStream_t stream) {
    const float* in = (const float*)d_in[0];   // (B, C_IN, N)
    const float* w  = (const float*)d_in[1];   // (C_OUT, K, C_IN)
    const float* sc = (const float*)d_in[2];   // (B, K, N)
    float* out = (float*)d_out;                // (B, C_OUT, N)

    TransformConv1d_39264591020709_kernel<<<GRID, 256, 0, stream>>>(in, w, sc, out);
}